// Round 12
// baseline (73.371 us; speedup 1.0000x reference)
//
#include <hip/hip_runtime.h>
#include <hip/hip_bf16.h>

// SparseMHA: N=4096, HID=512, 8 heads x 64 dim, fp32 in/out.
// softmax(A*scores), A ~1% binary =>
//   denom = 4096 + sum_nz (exp(s)-1);  out = (Vsum + sum_nz (exp(s)-1)*v)/denom
// GEMMs: bf16 MFMA (f32 accum), 2-phase dbuf (measured good in 68.5us run).
// QKV fused in ONE kernel pass: each block computes Q,K,V for one head's
// 128-row strip (A-tile staged once, 3 B-tiles, 24 MFMA/K-step).
// K/V fp8 e4m3, layout [h][m][dg][K8|V8] (one 16B load per (nz,lane)).
// Vsum via separate fence-free collapse kernel (R10: in-kernel threadfence
// collapse cost ~30us — never again). Q carries 512^-0.5*log2(e) -> exp2.
// NOTE (R8): do NOT mix A-scan blocks into the GEMM kernel (3x regression).

#define N_TOK 4096
#define HID   512
#define NHEAD 8
#define HDIM  64
#define QSCALE_F  0.06376070971402051f   // 512^-0.5 * log2(e)

// workspace layout (float-slot offsets)
#define QH_OFF    0u        // f32 [8][4096][64] head-major Q (scaled by QSCALE)
#define KVB_OFF   2097152u  // fp8 [8][4096][128B]: per (h,m): 8 groups x (K8|V8)
#define VSP_OFF   3145728u  // f32 [32 mb][512] V column-sum partials, [h*64+d]
#define VSUM_OFF  3162112u  // f32 [512] permuted [h*64+d]
#define CNT_OFF   3162624u  // i32 [4096] nonzero counts
#define LIST_OFF  3166720u  // i32 [4096][128] nonzero column lists
#define HB_OFF    3691008u  // bf16 [4096][512] h; reused as OPB [n][h*64+d]
#define WQKV_OFF  4739584u  // bf16 [3][512][512]
#define WO_OFF    5132800u  // bf16 [512][512], columns K-PERMUTED: [o][h*64+d]

typedef __attribute__((ext_vector_type(8))) short bf16x8;
typedef __attribute__((ext_vector_type(4))) float f32x4;
typedef __attribute__((ext_vector_type(2))) float f32x2;

__device__ __forceinline__ ushort f2bf(float f) {
    union { float f; unsigned u; } x; x.f = f;
    const unsigned r = x.u + 0x7fffu + ((x.u >> 16) & 1u);  // RNE
    return (ushort)(r >> 16);
}

#define GLOAD_LDS16(g, l) \
    __builtin_amdgcn_global_load_lds((const __attribute__((address_space(1))) void*)(g), \
                                     (__attribute__((address_space(3))) void*)(l), 16, 0, 0)

// ---------------------------------------------------------------------------
// prep: blocks 0..1023 scan A rows (ballot-compact nz lists, deterministic);
// blocks 1024..4095 convert h/Wq/Wk/Wv/Wo to bf16 (Wo with permuted columns).
// ---------------------------------------------------------------------------
__global__ __launch_bounds__(256) void prep(const float* __restrict__ A,
                                            const float* __restrict__ h,
                                            const float* __restrict__ wq,
                                            const float* __restrict__ wk,
                                            const float* __restrict__ wv,
                                            const float* __restrict__ wo,
                                            float* __restrict__ ws)
{
    const int bx = blockIdx.x;
    if (bx < 1024) {
        int* cnts  = (int*)(ws + CNT_OFF);
        int* lists = (int*)(ws + LIST_OFF);
        const int row  = bx * 4 + (threadIdx.x >> 6);
        const int lane = threadIdx.x & 63;
        const float4* Arow = (const float4*)(A + (size_t)row * N_TOK);
        int* out = lists + (size_t)row * 128;
        int cnt = 0;
#pragma unroll 4
        for (int it = 0; it < 16; ++it) {
            const float4 v = Arow[it * 64 + lane];
            const float vals[4] = {v.x, v.y, v.z, v.w};
#pragma unroll
            for (int j = 0; j < 4; ++j) {
                const bool nz = (vals[j] != 0.0f);
                const unsigned long long mask = __ballot(nz);
                if (nz) {
                    const int pos = cnt + __popcll(mask & ((1ull << lane) - 1ull));
                    if (pos < 128) out[pos] = it * 256 + lane * 4 + j;
                }
                cnt += __popcll(mask);
            }
        }
        if (lane == 0) cnts[row] = (cnt < 128) ? cnt : 128;
        return;
    }

    const int cb    = bx - 1024;
    const int chunk = cb >> 8;  // 0..11
    const int inner = (cb & 255) * 1024 + threadIdx.x * 4;
    ushort* hb    = (ushort*)(ws + HB_OFF);
    ushort* wqkvb = (ushort*)(ws + WQKV_OFF);
    ushort* wob   = (ushort*)(ws + WO_OFF);

    if (chunk < 11) {
        const float* src;
        ushort* dst;
        if (chunk < 8)       { src = h + (size_t)chunk * 262144; dst = hb + (size_t)chunk * 262144; }
        else if (chunk == 8) { src = wq; dst = wqkvb; }
        else if (chunk == 9) { src = wk; dst = wqkvb + 262144; }
        else                 { src = wv; dst = wqkvb + 524288; }
        const float4 v = *(const float4*)&src[inner];
        ushort4 o;
        o.x = f2bf(v.x); o.y = f2bf(v.y); o.z = f2bf(v.z); o.w = f2bf(v.w);
        *(ushort4*)&dst[inner] = o;
    } else {
        // Wo: permute columns j=d*8+h -> h*64+d (K-order permutation; matches OPB)
        const float4 v = *(const float4*)&wo[inner];
        const int o = inner >> 9;
        const int j0 = inner & 511;
        const float vals[4] = {v.x, v.y, v.z, v.w};
#pragma unroll
        for (int jj = 0; jj < 4; ++jj) {
            const int j = j0 + jj;
            wob[o * 512 + (j & 7) * 64 + (j >> 3)] = f2bf(vals[jj]);
        }
    }
}

// ---------------------------------------------------------------------------
// Fused QKV GEMM: one block = one head's 128-row strip, ALL of Q,K,V.
// A-tile (128x32) staged once/K-step + 3 B-tiles (64x32 strided W rows).
// 24 MFMA/K-step, 2-phase dbuf (40 KB LDS), grid (8 head, 32 mb), 1 block/CU.
// Epilogue: Q f32 (QSCALE), K/V fp8 group layout, V colsum partials -> VSP.
// ---------------------------------------------------------------------------
__global__ __launch_bounds__(256) void qkv_gemm_mfma(const float* __restrict__ ws_ro,
                                                     float* __restrict__ ws)
{
    const ushort* Xb = (const ushort*)(ws_ro + HB_OFF);
    const int hh  = blockIdx.x;
    const int mbi = blockIdx.y;
    const int mb  = mbi * 128;
    const ushort* Wb = (const ushort*)(ws_ro + WQKV_OFF);

    // per buffer: A 4096 shorts | B0 2048 | B1 2048 | B2 2048 = 10240 shorts
    __shared__ ushort SM[2 * 10240];  // 40 KB

    const int t    = threadIdx.x;
    const int w    = t >> 6;
    const int lane = t & 63;
    const int wr   = w >> 1, wc = w & 1;
    const int fr   = lane & 15;
    const int fq   = lane >> 4;
    const int fk   = fq * 8;

    const int srow = w * 16 + (lane >> 2);   // tile row for staging
    const int scol = (lane & 3) * 8;
    const ushort* gA  = Xb + (size_t)(mb + srow) * HID + scol;
    // B tile row r holds W row (hh + r*8): strided gather, linear LDS dest
    const ushort* gB0 = Wb + (size_t)(hh + srow * 8) * HID + scol;
    const ushort* gB1 = gB0 + 262144;
    const ushort* gB2 = gB0 + 524288;

#define QKV_STAGE(p, kb) do { \
        ushort* base_ = &SM[(p) * 10240]; \
        GLOAD_LDS16(gA  + (kb),            base_ + w * 512); \
        GLOAD_LDS16(gA  + (kb) + 64 * HID, base_ + 2048 + w * 512); \
        GLOAD_LDS16(gB0 + (kb),            base_ + 4096 + w * 512); \
        GLOAD_LDS16(gB1 + (kb),            base_ + 6144 + w * 512); \
        GLOAD_LDS16(gB2 + (kb),            base_ + 8192 + w * 512); \
    } while (0)

    f32x4 acc[3][4][2] = {};

    QKV_STAGE(0, 0);
    __syncthreads();
    for (int ts = 0; ts < 16; ++ts) {
        const int p = ts & 1;
        if (ts < 15) QKV_STAGE(p ^ 1, (ts + 1) * 32);
        const ushort* base = &SM[p * 10240];
        bf16x8 a[4], b[3][2];
#pragma unroll
        for (int mi = 0; mi < 4; ++mi)
            a[mi] = *(const bf16x8*)&base[(wr * 64 + mi * 16 + fr) * 32 + fk];
#pragma unroll
        for (int z = 0; z < 3; ++z)
#pragma unroll
            for (int ni = 0; ni < 2; ++ni)
                b[z][ni] = *(const bf16x8*)&base[4096 + z * 2048 + (wc * 32 + ni * 16 + fr) * 32 + fk];
#pragma unroll
        for (int z = 0; z < 3; ++z)
#pragma unroll
            for (int mi = 0; mi < 4; ++mi)
#pragma unroll
                for (int ni = 0; ni < 2; ++ni)
                    acc[z][mi][ni] = __builtin_amdgcn_mfma_f32_16x16x32_bf16(a[mi], b[z][ni], acc[z][mi][ni], 0, 0, 0);
        __syncthreads();
    }
#undef QKV_STAGE

    // tile col = d = wc*32 + ni*16 + fr; row m = mb + wr*64 + mi*16 + fq*4 + j
    // ---- Q (f32 head-major, QSCALE) ----
    {
        float* Yh = ws + QH_OFF + (size_t)hh * (N_TOK * HDIM);
#pragma unroll
        for (int ni = 0; ni < 2; ++ni) {
            const int d = wc * 32 + ni * 16 + fr;
#pragma unroll
            for (int mi = 0; mi < 4; ++mi) {
                const int r0 = mb + wr * 64 + mi * 16 + fq * 4;
#pragma unroll
                for (int j = 0; j < 4; ++j)
                    Yh[(size_t)(r0 + j) * HDIM + d] = acc[0][mi][ni][j] * QSCALE_F;
            }
        }
    }
    // ---- K and V (fp8, group layout: elem d -> (d>>3)*16 + (d&7), +8 for V) ----
    {
        unsigned char* KVh = (unsigned char*)(ws + KVB_OFF) + (size_t)hh * (N_TOK * 128);
#pragma unroll
        for (int z = 1; z < 3; ++z) {
            const int off = (z == 1) ? 0 : 8;
#pragma unroll
            for (int ni = 0; ni < 2; ++ni) {
                const int d = wc * 32 + ni * 16 + fr;
                const int doff = (d >> 3) * 16 + (d & 7) + off;
#pragma unroll
                for (int mi = 0; mi < 4; ++mi) {
                    const int r0 = mb + wr * 64 + mi * 16 + fq * 4;
#pragma unroll
                    for (int j = 0; j < 4; ++j) {
                        const float v = acc[z][mi][ni][j];
                        const int pk = __builtin_amdgcn_cvt_pk_fp8_f32(v, v, 0, false);
                        KVh[(size_t)(r0 + j) * 128 + doff] = (unsigned char)(pk & 0xff);
                    }
                }
            }
        }
    }
    // ---- V column partial sums (deterministic, from f32 accumulators) ----
    {
        __syncthreads();
        float* red = (float*)SM;  // [8][64] f32 scratch
#pragma unroll
        for (int ni = 0; ni < 2; ++ni) {
            float ps = 0.f;
#pragma unroll
            for (int mi = 0; mi < 4; ++mi)
#pragma unroll
                for (int j = 0; j < 4; ++j) ps += acc[2][mi][ni][j];
            red[(wr * 4 + fq) * 64 + wc * 32 + ni * 16 + fr] = ps;
        }
        __syncthreads();
        if (t < 64) {
            float s = 0.f;
#pragma unroll
            for (int r = 0; r < 8; ++r) s += red[r * 64 + t];
            ws[VSP_OFF + mbi * 512 + hh * 64 + t] = s;
        }
    }
}

// ---------------------------------------------------------------------------
// Collapse VSP -> Vsum_perm[h*64+d]. grid 8 (head), 64 threads (d).
// ---------------------------------------------------------------------------
__global__ __launch_bounds__(64) void vsum_collapse(float* __restrict__ ws)
{
    const float* VSP = ws + VSP_OFF;
    const int hh = blockIdx.x, d = threadIdx.x;
    float s = 0.f;
#pragma unroll
    for (int mb = 0; mb < 32; ++mb) s += VSP[mb * 512 + hh * 64 + d];
    ws[VSUM_OFF + hh * 64 + d] = s;
}

// ---------------------------------------------------------------------------
// Sparse attention. Grid 8192: b -> n = (b>>3)*4 + (b&3), hg = (b>>2)&1
// (bijective; under RR dispatch, each XCD sees 4 heads -> 2 MB fp8 KV in L2).
// Wave w -> head hg*4+w. lane = g*8+dg: 8 nz in parallel (g), 8 dims/lane.
// ONE 16B load per (nz, lane) = K8+V8; 2-wide unroll (proven best).
// weight = exp2(s) - 1 (log2e folded into Q).
// ---------------------------------------------------------------------------
__global__ __launch_bounds__(256) void attn_sparse(float* __restrict__ ws)
{
    const int b    = blockIdx.x;
    const int n    = (b >> 3) * 4 + (b & 3);
    const int hg   = (b >> 2) & 1;
    const int t    = threadIdx.x;
    const int w    = t >> 6;
    const int lane = t & 63;
    const int g    = lane >> 3;
    const int dg   = lane & 7;
    const int h    = hg * 4 + w;

    const int* cnts  = (const int*)(ws + CNT_OFF);
    const int* lists = (const int*)(ws + LIST_OFF);

    __shared__ int s_idx[128];
    const int cnt = cnts[n];
    if (t < 128) s_idx[t] = (t < cnt) ? lists[(size_t)n * 128 + t] : 0;
    __syncthreads();

    const float* Qh = ws + QH_OFF;
    const unsigned char* kvh = (const unsigned char*)(ws + KVB_OFF)
                             + (size_t)h * (N_TOK * 128) + dg * 16;
    ushort* opb = (ushort*)(ws + HB_OFF);  // OPB [n][h*64+d] bf16 (hb is dead)

    const float* qrow = Qh + ((size_t)h * N_TOK + n) * HDIM + dg * 8;
    const float4 qa = *(const float4*)qrow;
    const float4 qb = *(const float4*)(qrow + 4);

    float acc[8] = {0.f, 0.f, 0.f, 0.f, 0.f, 0.f, 0.f, 0.f};
    float den = 0.f;

    const int iters = (cnt + 7) >> 3;

#define ATTN_DOT(kw0, kw1, sval) do { \
        const f32x2 k0_ = __builtin_amdgcn_cvt_pk_f32_fp8((kw0), false); \
        const f32x2 k1_ = __builtin_amdgcn_cvt_pk_f32_fp8((kw0), true);  \
        const f32x2 k2_ = __builtin_amdgcn_cvt_pk_f32_fp8((kw1), false); \
        const f32x2 k3_ = __builtin_amdgcn_cvt_pk_f32_fp8((kw1), true);  \
        sval = qa.x * k0_[0] + qa.y * k0_[1] + qa.z * k1_[0] + qa.w * k1_[1] \
             + qb.x * k2_[0] + qb.y * k2_[1] + qb.z * k3_[0] + qb.w * k3_[1]; \
        sval += __shfl_xor(sval, 1); \
        sval += __shfl_xor(sval, 2); \
        sval += __shfl_xor(sval, 4); \
    } while (0)

#define ATTN_ACC(vw0, vw1, wgt) do { \
        const f32x2 v0_ = __builtin_amdgcn_cvt_pk_f32_fp8((vw0), false); \
        const f32x2 v1_ = __builtin_amdgcn_cvt_pk_f32_fp8((vw0), true);  \
        const f32x2 v2_ = __builtin_amdgcn_cvt_pk_f32_fp8((vw1), false); \
        const f32x2 v3_ = __builtin_amdgcn_cvt_pk_f32_fp8((vw1), true);  \
        acc[0] += (wgt) * v0_[0]; acc[1] += (wgt) * v0_[1]; \
        acc[2] += (wgt) * v1_[0]; acc[3] += (wgt) * v1_[1]; \
        acc[4] += (wgt) * v2_[0]; acc[5] += (wgt) * v2_[1]; \
        acc[6] += (wgt) * v3_[0]; acc[7] += (wgt) * v3_[1]; \
    } while (0)

    int i = 0;
    for (; i + 2 <= iters; i += 2) {
        const int j0 = i * 8 + g;           // <= 119
        const int j1 = j0 + 8;              // <= 127
        const int m0 = s_idx[j0];
        const int m1 = s_idx[j1];
        const uint4 kv0 = *(const uint4*)(kvh + (size_t)m0 * 128);
        const uint4 kv1 = *(const uint4*)(kvh + (size_t)m1 * 128);
        float s0, s1;
        ATTN_DOT(kv0.x, kv0.y, s0);
        ATTN_DOT(kv1.x, kv1.y, s1);
        const float w0 = (j0 < cnt) ? exp2f(s0) - 1.0f : 0.0f;
        const float w1 = (j1 < cnt) ? exp2f(s1) - 1.0f : 0.0f;
        ATTN_ACC(kv0.z, kv0.w, w0);
        ATTN_ACC(kv1.z, kv1.w, w1);
        den += w0;
        den += w1;
    }
    if (i < iters) {
        const int j0 = i * 8 + g;
        const int m0 = s_idx[j0 & 127];
        const uint4 kv0 = *(const uint4*)(kvh + (size_t)m0 * 128);
        float s0;
        ATTN_DOT(kv0.x, kv0.y, s0);
        const float w0 = (j0 < cnt) ? exp2f(s0) - 1.0f : 0.0f;
        ATTN_ACC(kv0.z, kv0.w, w0);
        den += w0;
    }
#undef ATTN_DOT
#undef ATTN_ACC

#pragma unroll
    for (int off = 8; off <= 32; off <<= 1) {
#pragma unroll
        for (int e = 0; e < 8; ++e) acc[e] += __shfl_xor(acc[e], off);
        den += __shfl_xor(den, off);
    }

    if (g == 0) {
        const float* vsp = ws + VSUM_OFF + h * 64 + dg * 8;
        const float4 va = *(const float4*)vsp;
        const float4 vb = *(const float4*)(vsp + 4);
        const float vs[8] = {va.x, va.y, va.z, va.w, vb.x, vb.y, vb.z, vb.w};
        const float r = 1.0f / (4096.0f + den);
        bf16x8 o;
#pragma unroll
        for (int e = 0; e < 8; ++e) o[e] = (short)f2bf((vs[e] + acc[e]) * r);
        *(bf16x8*)(opb + (size_t)n * HID + h * 64 + dg * 8) = o;
    }
}

// ---------------------------------------------------------------------------
// out = OPB @ Wo_perm^T -> d_out f32 (K-permuted both sides), 2-phase dbuf.
// 128x64 tile, grid (8, 32).
// ---------------------------------------------------------------------------
__global__ __launch_bounds__(256) void out_gemm_mfma(const float* __restrict__ ws_ro,
                                                     float* __restrict__ out)
{
    const ushort* Xb = (const ushort*)(ws_ro + HB_OFF);
    const ushort* W  = (const ushort*)(ws_ro + WO_OFF);

    const int nb = blockIdx.x * 64;
    const int mb = blockIdx.y * 128;

    __shared__ ushort SM[12288];  // 24KB double buffer

    const int t    = threadIdx.x;
    const int w    = t >> 6;
    const int lane = t & 63;
    const int wr   = w >> 1, wc = w & 1;
    const int fr   = lane & 15;
    const int fq   = lane >> 4;
    const int fk   = fq * 8;

    const int srow = w * 16 + (lane >> 2);
    const int scol = (lane & 3) * 8;
    const ushort* gA = Xb + (size_t)(mb + srow) * HID + scol;
    const ushort* gB = W  + (size_t)(nb + srow) * HID + scol;

#define OUT_STAGE(p, kb) do { \
        ushort* base_ = &SM[(p) * 6144]; \
        GLOAD_LDS16(gA + (kb),            base_ + w * 512); \
        GLOAD_LDS16(gA + (kb) + 64 * HID, base_ + 2048 + w * 512); \
        GLOAD_LDS16(gB + (kb),            base_ + 4096 + w * 512); \
    } while (0)

    f32x4 acc[4][2] = {};

    OUT_STAGE(0, 0);
    __syncthreads();
    for (int ts = 0; ts < 16; ++ts) {
        const int p = ts & 1;
        if (ts < 15) OUT_STAGE(p ^ 1, (ts + 1) * 32);
        const ushort* base = &SM[p * 6144];
        bf16x8 a[4], b[2];
#pragma unroll
        for (int mi = 0; mi < 4; ++mi)
            a[mi] = *(const bf16x8*)&base[(wr * 64 + mi * 16 + fr) * 32 + fk];
#pragma unroll
        for (int ni = 0; ni < 2; ++ni)
            b[ni] = *(const bf16x8*)&base[4096 + (wc * 32 + ni * 16 + fr) * 32 + fk];
#pragma unroll
        for (int mi = 0; mi < 4; ++mi)
#pragma unroll
            for (int ni = 0; ni < 2; ++ni)
                acc[mi][ni] = __builtin_amdgcn_mfma_f32_16x16x32_bf16(a[mi], b[ni], acc[mi][ni], 0, 0, 0);
        __syncthreads();
    }
#undef OUT_STAGE

#pragma unroll
    for (int ni = 0; ni < 2; ++ni) {
        const int col = nb + wc * 32 + ni * 16 + fr;
#pragma unroll
        for (int mi = 0; mi < 4; ++mi) {
            const int r0 = mb + wr * 64 + mi * 16 + fq * 4;
#pragma unroll
            for (int j = 0; j < 4; ++j)
                out[(size_t)(r0 + j) * HID + col] = acc[mi][ni][j];
        }
    }
}

// ---------------------------------------------------------------------------
extern "C" void kernel_launch(void* const* d_in, const int* in_sizes, int n_in,
                              void* d_out, int out_size, void* d_ws, size_t ws_size,
                              hipStream_t stream)
{
    const float* A  = (const float*)d_in[0];
    const float* h  = (const float*)d_in[1];
    const float* Wq = (const float*)d_in[2];
    const float* Wk = (const float*)d_in[3];
    const float* Wv = (const float*)d_in[4];
    const float* Wo = (const float*)d_in[5];
    float* out = (float*)d_out;
    float* ws  = (float*)d_ws;

    // 1) A-row nz lists + bf16 conversions (fused streaming pass)
    prep<<<dim3(4096), 256, 0, stream>>>(A, h, Wq, Wk, Wv, Wo, ws);
    // 2) fused QKV GEMM (dbuf, 1 block/CU): Q f32, K/V fp8 KVB + V colsums
    qkv_gemm_mfma<<<dim3(8, 32), 256, 0, stream>>>(ws, ws);
    // 3) collapse V colsum partials -> Vsum_perm (fence-free)
    vsum_collapse<<<dim3(8), 64, 0, stream>>>(ws);
    // 4) sparse attention -> bf16 OPB (K-permuted layout)
    attn_sparse<<<dim3(8192), 256, 0, stream>>>(ws);
    // 5) output projection (K-permuted Wo, dbuf) -> d_out f32
    out_gemm_mfma<<<dim3(8, 32), 256, 0, stream>>>(ws, out);
}

// Round 13
// 69.731 us; speedup vs baseline: 1.0522x; 1.0522x over previous
//
#include <hip/hip_runtime.h>
#include <hip/hip_bf16.h>

// SparseMHA: N=4096, HID=512, 8 heads x 64 dim, fp32 in/out.
// softmax(A*scores), A ~1% binary =>
//   denom = 4096 + sum_nz (exp(s)-1);  out = (Vsum + sum_nz (exp(s)-1)*v)/denom
// BEST-KNOWN CONFIG (68.5us run) + exp2f delta:
//   prep: A-scan + bf16 converts (fused streaming)
//   qkv: z-grid (8,32,3), 2-phase dbuf 24KB — dbuf worth ~3us on this shape
//   vsum_collapse: separate fence-free kernel (in-kernel threadfence = +30us, R9)
//   attn: KVB group layout [h][m][dg][K8|V8], one 16B load/(nz,lane), 2-wide
//         unroll, weight = exp2(s)-1 with log2e folded into Q scale
//   out: K-permuted Wo, dbuf
// NOTE (R8): never mix A-scan blocks into GEMM kernels (3x regression).
// NOTE (R11): fused 3-in-1 QKV (40KB LDS, 1 blk/CU) loses to z-grid dbuf.

#define N_TOK 4096
#define HID   512
#define NHEAD 8
#define HDIM  64
#define QSCALE_F  0.06376070971402051f   // 512^-0.5 * log2(e)

// workspace layout (float-slot offsets)
#define QH_OFF    0u        // f32 [8][4096][64] head-major Q (scaled by QSCALE)
#define KVB_OFF   2097152u  // fp8 [8][4096][128B]: per (h,m): 8 groups x (K8|V8)
#define VSP_OFF   3145728u  // f32 [32 mb][512] V column-sum partials, [h*64+d]
#define VSUM_OFF  3162112u  // f32 [512] permuted [h*64+d]
#define CNT_OFF   3162624u  // i32 [4096] nonzero counts
#define LIST_OFF  3166720u  // i32 [4096][128] nonzero column lists
#define HB_OFF    3691008u  // bf16 [4096][512] h; reused as OPB [n][h*64+d]
#define WQKV_OFF  4739584u  // bf16 [3][512][512]
#define WO_OFF    5132800u  // bf16 [512][512], columns K-PERMUTED: [o][h*64+d]

typedef __attribute__((ext_vector_type(8))) short bf16x8;
typedef __attribute__((ext_vector_type(4))) float f32x4;
typedef __attribute__((ext_vector_type(2))) float f32x2;

__device__ __forceinline__ ushort f2bf(float f) {
    union { float f; unsigned u; } x; x.f = f;
    const unsigned r = x.u + 0x7fffu + ((x.u >> 16) & 1u);  // RNE
    return (ushort)(r >> 16);
}

#define GLOAD_LDS16(g, l) \
    __builtin_amdgcn_global_load_lds((const __attribute__((address_space(1))) void*)(g), \
                                     (__attribute__((address_space(3))) void*)(l), 16, 0, 0)

// ---------------------------------------------------------------------------
// prep: blocks 0..1023 scan A rows (ballot-compact nz lists, deterministic);
// blocks 1024..4095 convert h/Wq/Wk/Wv/Wo to bf16 (Wo with permuted columns).
// ---------------------------------------------------------------------------
__global__ __launch_bounds__(256) void prep(const float* __restrict__ A,
                                            const float* __restrict__ h,
                                            const float* __restrict__ wq,
                                            const float* __restrict__ wk,
                                            const float* __restrict__ wv,
                                            const float* __restrict__ wo,
                                            float* __restrict__ ws)
{
    const int bx = blockIdx.x;
    if (bx < 1024) {
        int* cnts  = (int*)(ws + CNT_OFF);
        int* lists = (int*)(ws + LIST_OFF);
        const int row  = bx * 4 + (threadIdx.x >> 6);
        const int lane = threadIdx.x & 63;
        const float4* Arow = (const float4*)(A + (size_t)row * N_TOK);
        int* out = lists + (size_t)row * 128;
        int cnt = 0;
#pragma unroll 4
        for (int it = 0; it < 16; ++it) {
            const float4 v = Arow[it * 64 + lane];
            const float vals[4] = {v.x, v.y, v.z, v.w};
#pragma unroll
            for (int j = 0; j < 4; ++j) {
                const bool nz = (vals[j] != 0.0f);
                const unsigned long long mask = __ballot(nz);
                if (nz) {
                    const int pos = cnt + __popcll(mask & ((1ull << lane) - 1ull));
                    if (pos < 128) out[pos] = it * 256 + lane * 4 + j;
                }
                cnt += __popcll(mask);
            }
        }
        if (lane == 0) cnts[row] = (cnt < 128) ? cnt : 128;
        return;
    }

    const int cb    = bx - 1024;
    const int chunk = cb >> 8;  // 0..11
    const int inner = (cb & 255) * 1024 + threadIdx.x * 4;
    ushort* hb    = (ushort*)(ws + HB_OFF);
    ushort* wqkvb = (ushort*)(ws + WQKV_OFF);
    ushort* wob   = (ushort*)(ws + WO_OFF);

    if (chunk < 11) {
        const float* src;
        ushort* dst;
        if (chunk < 8)       { src = h + (size_t)chunk * 262144; dst = hb + (size_t)chunk * 262144; }
        else if (chunk == 8) { src = wq; dst = wqkvb; }
        else if (chunk == 9) { src = wk; dst = wqkvb + 262144; }
        else                 { src = wv; dst = wqkvb + 524288; }
        const float4 v = *(const float4*)&src[inner];
        ushort4 o;
        o.x = f2bf(v.x); o.y = f2bf(v.y); o.z = f2bf(v.z); o.w = f2bf(v.w);
        *(ushort4*)&dst[inner] = o;
    } else {
        // Wo: permute columns j=d*8+h -> h*64+d (K-order permutation; matches OPB)
        const float4 v = *(const float4*)&wo[inner];
        const int o = inner >> 9;
        const int j0 = inner & 511;
        const float vals[4] = {v.x, v.y, v.z, v.w};
#pragma unroll
        for (int jj = 0; jj < 4; ++jj) {
            const int j = j0 + jj;
            wob[o * 512 + (j & 7) * 64 + (j >> 3)] = f2bf(vals[jj]);
        }
    }
}

// ---------------------------------------------------------------------------
// bf16 MFMA GEMM, one head's 64 cols per block, 2-phase double-buffered.
// 128(M)x64(N=d) tile, BK=32, 4 waves (2x2), 4x2 fragments/wave.
// grid (8 head, 32 mb, 3 mat). z=0: Q -> f32 [h][n][64], QSCALE.
// z=1: K -> fp8 KVB group layout. z=2: V -> fp8 KVB + f32 colsum partials.
// ---------------------------------------------------------------------------
__global__ __launch_bounds__(256) void qkv_gemm_mfma(const float* __restrict__ ws_ro,
                                                     float* __restrict__ ws)
{
    const ushort* Xb = (const ushort*)(ws_ro + HB_OFF);
    const int z   = blockIdx.z;
    const int hh  = blockIdx.x;
    const int mbi = blockIdx.y;
    const int mb  = mbi * 128;
    const ushort* W = (const ushort*)(ws_ro + WQKV_OFF) + (size_t)z * 262144;

    __shared__ ushort SM[12288];  // 24KB: buf p at p*6144 = [A:4096 | B:2048]

    const int t    = threadIdx.x;
    const int w    = t >> 6;
    const int lane = t & 63;
    const int wr   = w >> 1, wc = w & 1;
    const int fr   = lane & 15;
    const int fq   = lane >> 4;
    const int fk   = fq * 8;

    const int srow = w * 16 + (lane >> 2);   // tile row for staging
    const int scol = (lane & 3) * 8;
    const ushort* gA = Xb + (size_t)(mb + srow) * HID + scol;
    // B tile row r holds W row (hh + r*8): strided gather, linear LDS dest
    const ushort* gB = W + (size_t)(hh + srow * 8) * HID + scol;

#define QKV_STAGE(p, kb) do { \
        ushort* base_ = &SM[(p) * 6144]; \
        GLOAD_LDS16(gA + (kb),            base_ + w * 512); \
        GLOAD_LDS16(gA + (kb) + 64 * HID, base_ + 2048 + w * 512); \
        GLOAD_LDS16(gB + (kb),            base_ + 4096 + w * 512); \
    } while (0)

    f32x4 acc[4][2] = {};

    QKV_STAGE(0, 0);
    __syncthreads();
    for (int ts = 0; ts < 16; ++ts) {
        const int p = ts & 1;
        if (ts < 15) QKV_STAGE(p ^ 1, (ts + 1) * 32);
        const ushort* base = &SM[p * 6144];
        bf16x8 a[4], b[2];
#pragma unroll
        for (int mi = 0; mi < 4; ++mi)
            a[mi] = *(const bf16x8*)&base[(wr * 64 + mi * 16 + fr) * 32 + fk];
#pragma unroll
        for (int ni = 0; ni < 2; ++ni)
            b[ni] = *(const bf16x8*)&base[4096 + (wc * 32 + ni * 16 + fr) * 32 + fk];
#pragma unroll
        for (int mi = 0; mi < 4; ++mi)
#pragma unroll
            for (int ni = 0; ni < 2; ++ni)
                acc[mi][ni] = __builtin_amdgcn_mfma_f32_16x16x32_bf16(a[mi], b[ni], acc[mi][ni], 0, 0, 0);
        __syncthreads();
    }
#undef QKV_STAGE

    // tile col = d = wc*32 + ni*16 + fr; row m = mb + wr*64 + mi*16 + fq*4 + j
    if (z == 0) {
        float* Yh = ws + QH_OFF + (size_t)hh * (N_TOK * HDIM);
#pragma unroll
        for (int ni = 0; ni < 2; ++ni) {
            const int d = wc * 32 + ni * 16 + fr;
#pragma unroll
            for (int mi = 0; mi < 4; ++mi) {
                const int r0 = mb + wr * 64 + mi * 16 + fq * 4;
#pragma unroll
                for (int j = 0; j < 4; ++j)
                    Yh[(size_t)(r0 + j) * HDIM + d] = acc[mi][ni][j] * QSCALE_F;
            }
        }
    } else {
        // group layout: elem d -> (d>>3)*16 + (d&7), +8 for V
        unsigned char* KVh = (unsigned char*)(ws + KVB_OFF)
                           + (size_t)hh * (N_TOK * 128) + ((z == 1) ? 0 : 8);
#pragma unroll
        for (int ni = 0; ni < 2; ++ni) {
            const int d = wc * 32 + ni * 16 + fr;
            const int doff = (d >> 3) * 16 + (d & 7);
#pragma unroll
            for (int mi = 0; mi < 4; ++mi) {
                const int r0 = mb + wr * 64 + mi * 16 + fq * 4;
#pragma unroll
                for (int j = 0; j < 4; ++j) {
                    const float v = acc[mi][ni][j];
                    const int p = __builtin_amdgcn_cvt_pk_fp8_f32(v, v, 0, false);
                    KVh[(size_t)(r0 + j) * 128 + doff] = (unsigned char)(p & 0xff);
                }
            }
        }
        if (z == 2) {
            // deterministic V column partial sums from f32 accumulators
            __syncthreads();
            float* red = (float*)SM;  // [8][64] f32 scratch
#pragma unroll
            for (int ni = 0; ni < 2; ++ni) {
                float ps = 0.f;
#pragma unroll
                for (int mi = 0; mi < 4; ++mi)
#pragma unroll
                    for (int j = 0; j < 4; ++j) ps += acc[mi][ni][j];
                red[(wr * 4 + fq) * 64 + wc * 32 + ni * 16 + fr] = ps;
            }
            __syncthreads();
            if (t < 64) {
                float s = 0.f;
#pragma unroll
                for (int r = 0; r < 8; ++r) s += red[r * 64 + t];
                ws[VSP_OFF + mbi * 512 + hh * 64 + t] = s;
            }
        }
    }
}

// ---------------------------------------------------------------------------
// Collapse VSP -> Vsum_perm[h*64+d]. grid 8 (head), 64 threads (d).
// ---------------------------------------------------------------------------
__global__ __launch_bounds__(64) void vsum_collapse(float* __restrict__ ws)
{
    const float* VSP = ws + VSP_OFF;
    const int hh = blockIdx.x, d = threadIdx.x;
    float s = 0.f;
#pragma unroll
    for (int mb = 0; mb < 32; ++mb) s += VSP[mb * 512 + hh * 64 + d];
    ws[VSUM_OFF + hh * 64 + d] = s;
}

// ---------------------------------------------------------------------------
// Sparse attention. Grid 8192: b -> n = (b>>3)*4 + (b&3), hg = (b>>2)&1
// (bijective; under RR dispatch, each XCD sees 4 heads -> 2 MB fp8 KV in L2).
// Wave w -> head hg*4+w. lane = g*8+dg: 8 nz in parallel (g), 8 dims/lane.
// ONE 16B load per (nz, lane) = K8+V8; 2-wide unroll (proven best).
// weight = exp2(s) - 1 (log2e folded into Q).
// ---------------------------------------------------------------------------
__global__ __launch_bounds__(256) void attn_sparse(float* __restrict__ ws)
{
    const int b    = blockIdx.x;
    const int n    = (b >> 3) * 4 + (b & 3);
    const int hg   = (b >> 2) & 1;
    const int t    = threadIdx.x;
    const int w    = t >> 6;
    const int lane = t & 63;
    const int g    = lane >> 3;
    const int dg   = lane & 7;
    const int h    = hg * 4 + w;

    const int* cnts  = (const int*)(ws + CNT_OFF);
    const int* lists = (const int*)(ws + LIST_OFF);

    __shared__ int s_idx[128];
    const int cnt = cnts[n];
    if (t < 128) s_idx[t] = (t < cnt) ? lists[(size_t)n * 128 + t] : 0;
    __syncthreads();

    const float* Qh = ws + QH_OFF;
    const unsigned char* kvh = (const unsigned char*)(ws + KVB_OFF)
                             + (size_t)h * (N_TOK * 128) + dg * 16;
    ushort* opb = (ushort*)(ws + HB_OFF);  // OPB [n][h*64+d] bf16 (hb is dead)

    const float* qrow = Qh + ((size_t)h * N_TOK + n) * HDIM + dg * 8;
    const float4 qa = *(const float4*)qrow;
    const float4 qb = *(const float4*)(qrow + 4);

    float acc[8] = {0.f, 0.f, 0.f, 0.f, 0.f, 0.f, 0.f, 0.f};
    float den = 0.f;

    const int iters = (cnt + 7) >> 3;

#define ATTN_DOT(kw0, kw1, sval) do { \
        const f32x2 k0_ = __builtin_amdgcn_cvt_pk_f32_fp8((kw0), false); \
        const f32x2 k1_ = __builtin_amdgcn_cvt_pk_f32_fp8((kw0), true);  \
        const f32x2 k2_ = __builtin_amdgcn_cvt_pk_f32_fp8((kw1), false); \
        const f32x2 k3_ = __builtin_amdgcn_cvt_pk_f32_fp8((kw1), true);  \
        sval = qa.x * k0_[0] + qa.y * k0_[1] + qa.z * k1_[0] + qa.w * k1_[1] \
             + qb.x * k2_[0] + qb.y * k2_[1] + qb.z * k3_[0] + qb.w * k3_[1]; \
        sval += __shfl_xor(sval, 1); \
        sval += __shfl_xor(sval, 2); \
        sval += __shfl_xor(sval, 4); \
    } while (0)

#define ATTN_ACC(vw0, vw1, wgt) do { \
        const f32x2 v0_ = __builtin_amdgcn_cvt_pk_f32_fp8((vw0), false); \
        const f32x2 v1_ = __builtin_amdgcn_cvt_pk_f32_fp8((vw0), true);  \
        const f32x2 v2_ = __builtin_amdgcn_cvt_pk_f32_fp8((vw1), false); \
        const f32x2 v3_ = __builtin_amdgcn_cvt_pk_f32_fp8((vw1), true);  \
        acc[0] += (wgt) * v0_[0]; acc[1] += (wgt) * v0_[1]; \
        acc[2] += (wgt) * v1_[0]; acc[3] += (wgt) * v1_[1]; \
        acc[4] += (wgt) * v2_[0]; acc[5] += (wgt) * v2_[1]; \
        acc[6] += (wgt) * v3_[0]; acc[7] += (wgt) * v3_[1]; \
    } while (0)

    int i = 0;
    for (; i + 2 <= iters; i += 2) {
        const int j0 = i * 8 + g;           // <= 119
        const int j1 = j0 + 8;              // <= 127
        const int m0 = s_idx[j0];
        const int m1 = s_idx[j1];
        const uint4 kv0 = *(const uint4*)(kvh + (size_t)m0 * 128);
        const uint4 kv1 = *(const uint4*)(kvh + (size_t)m1 * 128);
        float s0, s1;
        ATTN_DOT(kv0.x, kv0.y, s0);
        ATTN_DOT(kv1.x, kv1.y, s1);
        const float w0 = (j0 < cnt) ? exp2f(s0) - 1.0f : 0.0f;
        const float w1 = (j1 < cnt) ? exp2f(s1) - 1.0f : 0.0f;
        ATTN_ACC(kv0.z, kv0.w, w0);
        ATTN_ACC(kv1.z, kv1.w, w1);
        den += w0;
        den += w1;
    }
    if (i < iters) {
        const int j0 = i * 8 + g;
        const int m0 = s_idx[j0 & 127];
        const uint4 kv0 = *(const uint4*)(kvh + (size_t)m0 * 128);
        float s0;
        ATTN_DOT(kv0.x, kv0.y, s0);
        const float w0 = (j0 < cnt) ? exp2f(s0) - 1.0f : 0.0f;
        ATTN_ACC(kv0.z, kv0.w, w0);
        den += w0;
    }
#undef ATTN_DOT
#undef ATTN_ACC

#pragma unroll
    for (int off = 8; off <= 32; off <<= 1) {
#pragma unroll
        for (int e = 0; e < 8; ++e) acc[e] += __shfl_xor(acc[e], off);
        den += __shfl_xor(den, off);
    }

    if (g == 0) {
        const float* vsp = ws + VSUM_OFF + h * 64 + dg * 8;
        const float4 va = *(const float4*)vsp;
        const float4 vb = *(const float4*)(vsp + 4);
        const float vs[8] = {va.x, va.y, va.z, va.w, vb.x, vb.y, vb.z, vb.w};
        const float r = 1.0f / (4096.0f + den);
        bf16x8 o;
#pragma unroll
        for (int e = 0; e < 8; ++e) o[e] = (short)f2bf((vs[e] + acc[e]) * r);
        *(bf16x8*)(opb + (size_t)n * HID + h * 64 + dg * 8) = o;
    }
}

// ---------------------------------------------------------------------------
// out = OPB @ Wo_perm^T -> d_out f32 (K-permuted both sides), 2-phase dbuf.
// 128x64 tile, grid (8, 32).
// ---------------------------------------------------------------------------
__global__ __launch_bounds__(256) void out_gemm_mfma(const float* __restrict__ ws_ro,
                                                     float* __restrict__ out)
{
    const ushort* Xb = (const ushort*)(ws_ro + HB_OFF);
    const ushort* W  = (const ushort*)(ws_ro + WO_OFF);

    const int nb = blockIdx.x * 64;
    const int mb = blockIdx.y * 128;

    __shared__ ushort SM[12288];  // 24KB double buffer

    const int t    = threadIdx.x;
    const int w    = t >> 6;
    const int lane = t & 63;
    const int wr   = w >> 1, wc = w & 1;
    const int fr   = lane & 15;
    const int fq   = lane >> 4;
    const int fk   = fq * 8;

    const int srow = w * 16 + (lane >> 2);
    const int scol = (lane & 3) * 8;
    const ushort* gA = Xb + (size_t)(mb + srow) * HID + scol;
    const ushort* gB = W  + (size_t)(nb + srow) * HID + scol;

#define OUT_STAGE(p, kb) do { \
        ushort* base_ = &SM[(p) * 6144]; \
        GLOAD_LDS16(gA + (kb),            base_ + w * 512); \
        GLOAD_LDS16(gA + (kb) + 64 * HID, base_ + 2048 + w * 512); \
        GLOAD_LDS16(gB + (kb),            base_ + 4096 + w * 512); \
    } while (0)

    f32x4 acc[4][2] = {};

    OUT_STAGE(0, 0);
    __syncthreads();
    for (int ts = 0; ts < 16; ++ts) {
        const int p = ts & 1;
        if (ts < 15) OUT_STAGE(p ^ 1, (ts + 1) * 32);
        const ushort* base = &SM[p * 6144];
        bf16x8 a[4], b[2];
#pragma unroll
        for (int mi = 0; mi < 4; ++mi)
            a[mi] = *(const bf16x8*)&base[(wr * 64 + mi * 16 + fr) * 32 + fk];
#pragma unroll
        for (int ni = 0; ni < 2; ++ni)
            b[ni] = *(const bf16x8*)&base[4096 + (wc * 32 + ni * 16 + fr) * 32 + fk];
#pragma unroll
        for (int mi = 0; mi < 4; ++mi)
#pragma unroll
            for (int ni = 0; ni < 2; ++ni)
                acc[mi][ni] = __builtin_amdgcn_mfma_f32_16x16x32_bf16(a[mi], b[ni], acc[mi][ni], 0, 0, 0);
        __syncthreads();
    }
#undef OUT_STAGE

#pragma unroll
    for (int ni = 0; ni < 2; ++ni) {
        const int col = nb + wc * 32 + ni * 16 + fr;
#pragma unroll
        for (int mi = 0; mi < 4; ++mi) {
            const int r0 = mb + wr * 64 + mi * 16 + fq * 4;
#pragma unroll
            for (int j = 0; j < 4; ++j)
                out[(size_t)(r0 + j) * HID + col] = acc[mi][ni][j];
        }
    }
}

// ---------------------------------------------------------------------------
extern "C" void kernel_launch(void* const* d_in, const int* in_sizes, int n_in,
                              void* d_out, int out_size, void* d_ws, size_t ws_size,
                              hipStream_t stream)
{
    const float* A  = (const float*)d_in[0];
    const float* h  = (const float*)d_in[1];
    const float* Wq = (const float*)d_in[2];
    const float* Wk = (const float*)d_in[3];
    const float* Wv = (const float*)d_in[4];
    const float* Wo = (const float*)d_in[5];
    float* out = (float*)d_out;
    float* ws  = (float*)d_ws;

    // 1) A-row nz lists + bf16 conversions (fused streaming pass)
    prep<<<dim3(4096), 256, 0, stream>>>(A, h, Wq, Wk, Wv, Wo, ws);
    // 2) per-head QKV GEMM (z-grid, 2-phase dbuf): Q f32, K/V fp8 + V colsums
    qkv_gemm_mfma<<<dim3(8, 32, 3), 256, 0, stream>>>(ws, ws);
    // 3) collapse V colsum partials -> Vsum_perm (fence-free)
    vsum_collapse<<<dim3(8), 64, 0, stream>>>(ws);
    // 4) sparse attention -> bf16 OPB (K-permuted layout)
    attn_sparse<<<dim3(8192), 256, 0, stream>>>(ws);
    // 5) output projection (K-permuted Wo, dbuf) -> d_out f32
    out_gemm_mfma<<<dim3(8, 32), 256, 0, stream>>>(ws, out);
}